// Round 1
// 1440.322 us; speedup vs baseline: 1.0530x; 1.0530x over previous
//
#include <hip/hip_runtime.h>
#include <hip/hip_bf16.h>
#include <hip/hip_fp16.h>

#define D 512

typedef _Float16 half8 __attribute__((ext_vector_type(8)));
typedef _Float16 half4v __attribute__((ext_vector_type(4)));
typedef float floatx4 __attribute__((ext_vector_type(4)));

// ---------------- conversion kernels ----------------

__global__ void k_f32_to_f16(const float* __restrict__ in, _Float16* __restrict__ out, int n4) {
  int i = blockIdx.x * blockDim.x + threadIdx.x;
  if (i >= n4) return;
  // x is read exactly once -> non-temporal, keep L3 free for reused data
  floatx4 v = __builtin_nontemporal_load((const floatx4*)in + i);
  half4v h;
  h[0] = (_Float16)v[0]; h[1] = (_Float16)v[1]; h[2] = (_Float16)v[2]; h[3] = (_Float16)v[3];
  ((half4v*)out)[i] = h;  // reused 12x by GEMM -> cacheable
}

// wT[jg][k] = w_m[k][j],  jg = m*512 + j  (B^T layout for MFMA)
__global__ void k_build_wt(const float* __restrict__ w1, const float* __restrict__ w2,
                           const float* __restrict__ w3, _Float16* __restrict__ wT) {
  int id = blockIdx.x * blockDim.x + threadIdx.x;
  if (id >= 3 * D * D) return;
  int jg = id >> 9;
  int k  = id & (D - 1);
  const float* w = (jg < D) ? w1 : (jg < 2 * D ? w2 : w3);
  int j = jg & (D - 1);
  wT[id] = (_Float16)w[k * D + j];
}

// ---------------- CSR build ----------------

__global__ void k_count(const int* __restrict__ row, int* __restrict__ counts, int E) {
  int i = blockIdx.x * blockDim.x + threadIdx.x;
  if (i < E) atomicAdd(&counts[row[i]], 1);
}

// multi-block exclusive scan, phase 1: per-block (1024 elems) scan + block sums
__global__ __launch_bounds__(256) void k_scan1(const int* __restrict__ in, int* __restrict__ out,
                                               int* __restrict__ bsums, int n) {
  __shared__ int wsum[4];
  int t = threadIdx.x, lane = t & 63, wd = t >> 6;
  int i0 = blockIdx.x * 1024 + t * 4;
  int4 c = make_int4(0, 0, 0, 0);
  if (i0 + 3 < n) c = *(const int4*)(in + i0);
  else {
    if (i0 < n) c.x = in[i0];
    if (i0 + 1 < n) c.y = in[i0 + 1];
    if (i0 + 2 < n) c.z = in[i0 + 2];
  }
  int s1 = c.x, s2 = s1 + c.y, s3 = s2 + c.z, s4 = s3 + c.w;
  int x = s4;
#pragma unroll
  for (int o = 1; o < 64; o <<= 1) { int p = __shfl_up(x, o); if (lane >= o) x += p; }
  if (lane == 63) wsum[wd] = x;
  __syncthreads();
  int wex = 0;
  for (int k = 0; k < wd; ++k) wex += wsum[k];
  int base = wex + x - s4;
  if (i0 + 3 < n) *(int4*)(out + i0) = make_int4(base, base + s1, base + s2, base + s3);
  else {
    if (i0 < n) out[i0] = base;
    if (i0 + 1 < n) out[i0 + 1] = base + s1;
    if (i0 + 2 < n) out[i0 + 2] = base + s2;
  }
  if (t == 0) bsums[blockIdx.x] = wsum[0] + wsum[1] + wsum[2] + wsum[3];
}

// phase 2: single small block scans block sums (nb <= 128), writes grand total
__global__ void k_scan2(int* __restrict__ bsums, int* __restrict__ total_out, int nb) {
  __shared__ int w0;
  int t = threadIdx.x, lane = t & 63, wd = t >> 6;
  int v = (t < nb) ? bsums[t] : 0;
  int x = v;
#pragma unroll
  for (int o = 1; o < 64; o <<= 1) { int p = __shfl_up(x, o); if (lane >= o) x += p; }
  if (wd == 0 && lane == 63) w0 = x;
  __syncthreads();
  int excl = x - v + (wd ? w0 : 0);
  if (t < nb) bsums[t] = excl;
  if (t == 127) *total_out = w0 + x;
}

// phase 3: add scanned block sums
__global__ __launch_bounds__(256) void k_scan3(int* __restrict__ out, const int* __restrict__ bsums, int n) {
  int t = threadIdx.x;
  int i0 = blockIdx.x * 1024 + t * 4;
  int add = bsums[blockIdx.x];
  if (i0 + 3 < n) {
    int4 v = *(int4*)(out + i0);
    v.x += add; v.y += add; v.z += add; v.w += add;
    *(int4*)(out + i0) = v;
  } else {
    for (int k = 0; k < 4; ++k) if (i0 + k < n) out[i0 + k] += add;
  }
}

__global__ void k_scatter(const int* __restrict__ row, const int* __restrict__ col,
                          const float* __restrict__ val, const int* __restrict__ offsets,
                          int* __restrict__ cursor, long long* __restrict__ edges, int E) {
  int i = blockIdx.x * blockDim.x + threadIdx.x;
  if (i >= E) return;
  int r = row[i];  // second read of row[] (k_count was first) -> cacheable
  int c = __builtin_nontemporal_load(col + i);
  float v = __builtin_nontemporal_load(val + i);
  int p = offsets[r] + atomicAdd(&cursor[r], 1);
  long long pack = ((long long)(unsigned)__float_as_int(v) << 32) | (unsigned)c;
  __builtin_nontemporal_store(pack, edges + p);
}

// ---------------- fused triple GEMM (m97-style: global_load_lds width=16) -------
// C = x @ [w1 | w2 | w3]; support=f16, trans=+b2 (fp32 -> d_out), gate=sigmoid(+b3) f16.
// 128x128 tile, 4 waves each 64x64. LDS chunk XOR-swizzle: stored chunk position
// c_store = chunk ^ ((row>>1)&3)  ->  ds_read_b128 aliasing <= 2-way (free).
__global__ __launch_bounds__(256) void k_gemm(
    const _Float16* __restrict__ A,   // [M][512] f16
    const _Float16* __restrict__ BT,  // [1536][512] f16
    const float* __restrict__ b2, const float* __restrict__ b3,
    _Float16* __restrict__ support, float* __restrict__ trans,
    _Float16* __restrict__ gate, int M)
{
  __shared__ __align__(16) _Float16 ldsA[128 * 32];
  __shared__ __align__(16) _Float16 ldsB[128 * 32];
  int t = threadIdx.x;
  int colBase = blockIdx.x * 128;
  int rowBase = blockIdx.y * 128;
  int w = t >> 6, lane = t & 63, lr = lane & 15, quad = lane >> 4;
  int wrow = (w >> 1) * 64, wcol = (w & 1) * 64;
  floatx4 acc[4][4] = {};

  // staging: wave w stages rows [w*32, w*32+32), 2 DMA calls x 16 rows x 64B
  int srow0 = w * 32 + (lane >> 2);
  int schunk = lane & 3;

  for (int k0 = 0; k0 < D; k0 += 32) {
#pragma unroll
    for (int c = 0; c < 2; ++c) {
      int srow = srow0 + c * 16;
      int chunk = schunk ^ ((srow >> 1) & 3);   // data chunk stored at this slot
      int ga = rowBase + srow; if (ga >= M) ga = M - 1;
      const _Float16* gA = A + (size_t)ga * D + k0 + chunk * 8;
      const _Float16* gB = BT + (size_t)(colBase + srow) * D + k0 + chunk * 8;
      _Float16* lA = &ldsA[(w * 32 + c * 16) * 32];
      _Float16* lB = &ldsB[(w * 32 + c * 16) * 32];
      __builtin_amdgcn_global_load_lds((const __attribute__((address_space(1))) void*)gA,
                                       (__attribute__((address_space(3))) void*)lA, 16, 0, 0);
      __builtin_amdgcn_global_load_lds((const __attribute__((address_space(1))) void*)gB,
                                       (__attribute__((address_space(3))) void*)lB, 16, 0, 0);
    }
    __syncthreads();
    half8 af[4], bf[4];
#pragma unroll
    for (int i2 = 0; i2 < 4; ++i2) {
      int r = wrow + i2 * 16 + lr;
      af[i2] = *(const half8*)&ldsA[r * 32 + ((quad ^ ((r >> 1) & 3)) << 3)];
    }
#pragma unroll
    for (int j = 0; j < 4; ++j) {
      int r = wcol + j * 16 + lr;
      bf[j] = *(const half8*)&ldsB[r * 32 + ((quad ^ ((r >> 1) & 3)) << 3)];
    }
#pragma unroll
    for (int i2 = 0; i2 < 4; ++i2)
#pragma unroll
      for (int j = 0; j < 4; ++j)
        acc[i2][j] = __builtin_amdgcn_mfma_f32_16x16x32_f16(af[i2], bf[j], acc[i2][j], 0, 0, 0);
    __syncthreads();
  }

  // C/D layout: col = lane&15, row = quad*4 + reg
  // support stays cacheable (k_agg gathers it, 102MB fits L3);
  // trans/gate are read-once streams -> non-temporal stores.
#pragma unroll
  for (int i2 = 0; i2 < 4; ++i2) {
    int r0 = rowBase + wrow + i2 * 16 + quad * 4;
#pragma unroll
    for (int j = 0; j < 4; ++j) {
      int c = colBase + wcol + j * 16 + lr;
#pragma unroll
      for (int rg = 0; rg < 4; ++rg) {
        int r = r0 + rg;
        if (r >= M) continue;
        float v = acc[i2][j][rg];
        if (c < D) {
          support[(size_t)r * D + c] = (_Float16)v;
        } else if (c < 2 * D) {
          __builtin_nontemporal_store(v + b2[c - D], &trans[(size_t)r * D + (c - D)]);
        } else {
          int cc = c - 2 * D;
          float gv = v + b3[cc];
          gv = 1.0f / (1.0f + __expf(-gv));
          __builtin_nontemporal_store((_Float16)gv, &gate[(size_t)r * D + cc]);
        }
      }
    }
  }
}

// ---------------- aggregation + fused epilogue ----------------
// one wave per node; lane handles 8 channels. Per 64-edge chunk: load one edge
// per lane, bitonic-sort by col in registers, then shfl-broadcast edges,
// gather 8-deep (MLP). All read-once streams (edges/out/gate) are non-temporal
// so support[] (102MB) stays L3-resident across the whole kernel.
__global__ __launch_bounds__(256) void k_agg(
    const _Float16* __restrict__ support, const _Float16* __restrict__ gate,
    float* __restrict__ out, const float* __restrict__ b1,
    const int* __restrict__ offsets, const long long* __restrict__ edges, int n)
{
  int wid = (blockIdx.x * 256 + threadIdx.x) >> 6;
  if (wid >= n) return;
  int lane = threadIdx.x & 63;
  int s = offsets[wid], e = offsets[wid + 1];
  float acc[8] = {0, 0, 0, 0, 0, 0, 0, 0};
  const half8* sup8 = (const half8*)support;

  for (int base = s; base < e; base += 64) {
    int cnt = e - base; if (cnt > 64) cnt = 64;
    int key = 0x7fffffff; float val = 0.f;
    if (lane < cnt) {
      long long ed = __builtin_nontemporal_load(edges + base + lane);
      key = (int)(unsigned)(ed & 0xffffffffll);
      val = __int_as_float((int)(ed >> 32));
    }
    // 64-lane bitonic sort (key=col, payload=val)
#pragma unroll
    for (int size = 2; size <= 64; size <<= 1) {
#pragma unroll
      for (int stride = size >> 1; stride; stride >>= 1) {
        int pk = __shfl_xor(key, stride);
        float pv = __shfl_xor(val, stride);
        bool upper = (lane & stride) != 0;
        bool desc = (lane & size) != 0;
        bool takemax = upper != desc;
        bool swap = takemax ? (pk > key) : (pk < key);
        if (swap) { key = pk; val = pv; }
      }
    }
    int i = 0;
    // 8-deep gather: 8 independent 16B loads in flight per lane
    for (; i + 8 <= cnt; i += 8) {
      int cc[8]; float vv[8];
#pragma unroll
      for (int u = 0; u < 8; ++u) { cc[u] = __shfl(key, i + u); vv[u] = __shfl(val, i + u); }
      half8 h[8];
#pragma unroll
      for (int u = 0; u < 8; ++u) h[u] = sup8[(size_t)cc[u] * 64 + lane];
#pragma unroll
      for (int j = 0; j < 8; ++j) {
        float a = acc[j];
#pragma unroll
        for (int u = 0; u < 8; ++u) a += vv[u] * (float)h[u][j];
        acc[j] = a;
      }
    }
    for (; i + 4 <= cnt; i += 4) {
      int c0 = __shfl(key, i),     c1 = __shfl(key, i + 1);
      int c2 = __shfl(key, i + 2), c3 = __shfl(key, i + 3);
      float v0 = __shfl(val, i),     v1 = __shfl(val, i + 1);
      float v2 = __shfl(val, i + 2), v3 = __shfl(val, i + 3);
      half8 h0 = sup8[(size_t)c0 * 64 + lane];
      half8 h1 = sup8[(size_t)c1 * 64 + lane];
      half8 h2 = sup8[(size_t)c2 * 64 + lane];
      half8 h3 = sup8[(size_t)c3 * 64 + lane];
#pragma unroll
      for (int j = 0; j < 8; ++j)
        acc[j] += v0 * (float)h0[j] + v1 * (float)h1[j] + v2 * (float)h2[j] + v3 * (float)h3[j];
    }
    for (; i < cnt; ++i) {
      int c0 = __shfl(key, i);
      float v0 = __shfl(val, i);
      half8 h0 = sup8[(size_t)c0 * 64 + lane];
#pragma unroll
      for (int j = 0; j < 8; ++j) acc[j] += v0 * (float)h0[j];
    }
  }

  int base4 = wid * 128 + lane * 2;  // float4 units
  floatx4 t0 = __builtin_nontemporal_load((const floatx4*)out + base4);
  floatx4 t1 = __builtin_nontemporal_load((const floatx4*)out + base4 + 1);
  half8 g = __builtin_nontemporal_load((const half8*)gate + (size_t)wid * 64 + lane);
  floatx4 bb0 = ((const floatx4*)b1)[lane * 2];
  floatx4 bb1 = ((const floatx4*)b1)[lane * 2 + 1];
  float tt[8]  = {t0[0], t0[1], t0[2], t0[3], t1[0], t1[1], t1[2], t1[3]};
  float bbv[8] = {bb0[0], bb0[1], bb0[2], bb0[3], bb1[0], bb1[1], bb1[2], bb1[3]};
  float res[8];
#pragma unroll
  for (int j = 0; j < 8; ++j) {
    float o = acc[j] + bbv[j];
    o = o > 0.f ? o : 0.f;
    res[j] = tt[j] + (float)g[j] * (o - tt[j]);
  }
  floatx4 r0, r1;
  r0[0] = res[0]; r0[1] = res[1]; r0[2] = res[2]; r0[3] = res[3];
  r1[0] = res[4]; r1[1] = res[5]; r1[2] = res[6]; r1[3] = res[7];
  __builtin_nontemporal_store(r0, (floatx4*)out + base4);
  __builtin_nontemporal_store(r1, (floatx4*)out + base4 + 1);
}

// ---------------- launch ----------------

extern "C" void kernel_launch(void* const* d_in, const int* in_sizes, int n_in,
                              void* d_out, int out_size, void* d_ws, size_t ws_size,
                              hipStream_t stream) {
  const float* x    = (const float*)d_in[0];
  const float* w1   = (const float*)d_in[1];
  const float* w2   = (const float*)d_in[2];
  const float* w3   = (const float*)d_in[3];
  const float* b1   = (const float*)d_in[4];
  const float* b2   = (const float*)d_in[5];
  const float* b3   = (const float*)d_in[6];
  const int*   erow = (const int*)d_in[7];
  const int*   ecol = (const int*)d_in[8];
  const float* eval = (const float*)d_in[9];
  float* out = (float*)d_out;

  int N = in_sizes[0] / D;  // 100000
  int E = in_sizes[7];      // 3200000

  char* ws = (char*)d_ws;
  size_t off = 0;
  auto take = [&](size_t bytes) -> char* {
    char* p = ws + off;
    off += (bytes + 255) & ~(size_t)255;
    return p;
  };
  _Float16* xh    = (_Float16*)take((size_t)N * D * 2);
  _Float16* wT    = (_Float16*)take((size_t)3 * D * D * 2);
  _Float16* sup   = (_Float16*)take((size_t)N * D * 2);
  _Float16* gate  = (_Float16*)take((size_t)N * D * 2);
  int* counts     = (int*)take((size_t)N * 4);
  int* cursor     = (int*)take((size_t)N * 4);
  int* offsets    = (int*)take((size_t)(N + 1) * 4);
  int* bsums      = (int*)take(128 * 4);
  long long* edges = (long long*)take((size_t)E * 8);

  hipMemsetAsync(counts, 0, (size_t)N * 4, stream);
  hipMemsetAsync(cursor, 0, (size_t)N * 4, stream);

  int n4 = N * D / 4;
  k_f32_to_f16<<<(n4 + 255) / 256, 256, 0, stream>>>(x, xh, n4);
  k_build_wt<<<(3 * D * D + 255) / 256, 256, 0, stream>>>(w1, w2, w3, wT);
  k_count<<<(E + 255) / 256, 256, 0, stream>>>(erow, counts, E);
  int nb = (N + 1023) / 1024;
  k_scan1<<<nb, 256, 0, stream>>>(counts, offsets, bsums, N);
  k_scan2<<<1, 128, 0, stream>>>(bsums, offsets + N, nb);
  k_scan3<<<nb, 256, 0, stream>>>(offsets, bsums, N);
  k_scatter<<<(E + 255) / 256, 256, 0, stream>>>(erow, ecol, eval, offsets, cursor, edges, E);
  dim3 gg(3 * D / 128, (N + 127) / 128);
  k_gemm<<<gg, 256, 0, stream>>>(xh, wT, b2, b3, sup, out, gate, N);
  k_agg<<<((size_t)N * 64 + 255) / 256, 256, 0, stream>>>(sup, gate, out, b1, offsets, edges, N);
}

// Round 2
// 1369.493 us; speedup vs baseline: 1.1075x; 1.0517x over previous
//
#include <hip/hip_runtime.h>
#include <hip/hip_bf16.h>
#include <hip/hip_fp16.h>

#define D 512

typedef _Float16 half8 __attribute__((ext_vector_type(8)));
typedef _Float16 half4v __attribute__((ext_vector_type(4)));
typedef float floatx4 __attribute__((ext_vector_type(4)));

// ---------------- conversion kernels ----------------

__global__ void k_f32_to_f16(const float* __restrict__ in, _Float16* __restrict__ out, int n4) {
  int i = blockIdx.x * blockDim.x + threadIdx.x;
  if (i >= n4) return;
  floatx4 v = __builtin_nontemporal_load((const floatx4*)in + i);
  half4v h;
  h[0] = (_Float16)v[0]; h[1] = (_Float16)v[1]; h[2] = (_Float16)v[2]; h[3] = (_Float16)v[3];
  ((half4v*)out)[i] = h;  // xh reused by agg + GEMM -> cacheable
}

// wT[jg][k] = w_m[k][j],  jg = m*512 + j  (B^T layout for MFMA)
__global__ void k_build_wt(const float* __restrict__ w1, const float* __restrict__ w2,
                           const float* __restrict__ w3, _Float16* __restrict__ wT) {
  int id = blockIdx.x * blockDim.x + threadIdx.x;
  if (id >= 3 * D * D) return;
  int jg = id >> 9;
  int k  = id & (D - 1);
  const float* w = (jg < D) ? w1 : (jg < 2 * D ? w2 : w3);
  int j = jg & (D - 1);
  wT[id] = (_Float16)w[k * D + j];
}

// ---------------- CSR build ----------------

__global__ void k_count(const int* __restrict__ row, int* __restrict__ counts, int E) {
  int i = blockIdx.x * blockDim.x + threadIdx.x;
  if (i < E) atomicAdd(&counts[row[i]], 1);
}

__global__ __launch_bounds__(256) void k_scan1(const int* __restrict__ in, int* __restrict__ out,
                                               int* __restrict__ bsums, int n) {
  __shared__ int wsum[4];
  int t = threadIdx.x, lane = t & 63, wd = t >> 6;
  int i0 = blockIdx.x * 1024 + t * 4;
  int4 c = make_int4(0, 0, 0, 0);
  if (i0 + 3 < n) c = *(const int4*)(in + i0);
  else {
    if (i0 < n) c.x = in[i0];
    if (i0 + 1 < n) c.y = in[i0 + 1];
    if (i0 + 2 < n) c.z = in[i0 + 2];
  }
  int s1 = c.x, s2 = s1 + c.y, s3 = s2 + c.z, s4 = s3 + c.w;
  int x = s4;
#pragma unroll
  for (int o = 1; o < 64; o <<= 1) { int p = __shfl_up(x, o); if (lane >= o) x += p; }
  if (lane == 63) wsum[wd] = x;
  __syncthreads();
  int wex = 0;
  for (int k = 0; k < wd; ++k) wex += wsum[k];
  int base = wex + x - s4;
  if (i0 + 3 < n) *(int4*)(out + i0) = make_int4(base, base + s1, base + s2, base + s3);
  else {
    if (i0 < n) out[i0] = base;
    if (i0 + 1 < n) out[i0 + 1] = base + s1;
    if (i0 + 2 < n) out[i0 + 2] = base + s2;
  }
  if (t == 0) bsums[blockIdx.x] = wsum[0] + wsum[1] + wsum[2] + wsum[3];
}

__global__ void k_scan2(int* __restrict__ bsums, int* __restrict__ total_out, int nb) {
  __shared__ int w0;
  int t = threadIdx.x, lane = t & 63, wd = t >> 6;
  int v = (t < nb) ? bsums[t] : 0;
  int x = v;
#pragma unroll
  for (int o = 1; o < 64; o <<= 1) { int p = __shfl_up(x, o); if (lane >= o) x += p; }
  if (wd == 0 && lane == 63) w0 = x;
  __syncthreads();
  int excl = x - v + (wd ? w0 : 0);
  if (t < nb) bsums[t] = excl;
  if (t == 127) *total_out = w0 + x;
}

__global__ __launch_bounds__(256) void k_scan3(int* __restrict__ out, const int* __restrict__ bsums, int n) {
  int t = threadIdx.x;
  int i0 = blockIdx.x * 1024 + t * 4;
  int add = bsums[blockIdx.x];
  if (i0 + 3 < n) {
    int4 v = *(int4*)(out + i0);
    v.x += add; v.y += add; v.z += add; v.w += add;
    *(int4*)(out + i0) = v;
  } else {
    for (int k = 0; k < 4; ++k) if (i0 + k < n) out[i0 + k] += add;
  }
}

__global__ void k_scatter(const int* __restrict__ row, const int* __restrict__ col,
                          const float* __restrict__ val, const int* __restrict__ offsets,
                          int* __restrict__ cursor, long long* __restrict__ edges, int E) {
  int i = blockIdx.x * blockDim.x + threadIdx.x;
  if (i >= E) return;
  int r = row[i];
  int c = __builtin_nontemporal_load(col + i);
  float v = __builtin_nontemporal_load(val + i);
  int p = offsets[r] + atomicAdd(&cursor[r], 1);
  long long pack = ((long long)(unsigned)__float_as_int(v) << 32) | (unsigned)c;
  __builtin_nontemporal_store(pack, edges + p);
}

// ---------------- sparse aggregation on xh:  y = A_sp @ xh  (f16 out) --------
// Reassociation: agg = (A @ x) @ w1, so aggregate raw features BEFORE the GEMM.
// One wave per node; lane handles 8 channels; bitonic-sort 64-edge chunks by
// col; 8-deep gather for MLP. No stream reads left besides edges -> xh (102MB)
// gets the whole MALL to itself.
__global__ __launch_bounds__(256) void k_agg(
    const _Float16* __restrict__ xh, _Float16* __restrict__ yh,
    const int* __restrict__ offsets, const long long* __restrict__ edges, int n)
{
  int wid = (blockIdx.x * 256 + threadIdx.x) >> 6;
  if (wid >= n) return;
  int lane = threadIdx.x & 63;
  int s = offsets[wid], e = offsets[wid + 1];
  float acc[8] = {0, 0, 0, 0, 0, 0, 0, 0};
  const half8* x8 = (const half8*)xh;

  for (int base = s; base < e; base += 64) {
    int cnt = e - base; if (cnt > 64) cnt = 64;
    int key = 0x7fffffff; float val = 0.f;
    if (lane < cnt) {
      long long ed = __builtin_nontemporal_load(edges + base + lane);
      key = (int)(unsigned)(ed & 0xffffffffll);
      val = __int_as_float((int)(ed >> 32));
    }
#pragma unroll
    for (int size = 2; size <= 64; size <<= 1) {
#pragma unroll
      for (int stride = size >> 1; stride; stride >>= 1) {
        int pk = __shfl_xor(key, stride);
        float pv = __shfl_xor(val, stride);
        bool upper = (lane & stride) != 0;
        bool desc = (lane & size) != 0;
        bool takemax = upper != desc;
        bool swap = takemax ? (pk > key) : (pk < key);
        if (swap) { key = pk; val = pv; }
      }
    }
    int i = 0;
    for (; i + 8 <= cnt; i += 8) {
      int cc[8]; float vv[8];
#pragma unroll
      for (int u = 0; u < 8; ++u) { cc[u] = __shfl(key, i + u); vv[u] = __shfl(val, i + u); }
      half8 h[8];
#pragma unroll
      for (int u = 0; u < 8; ++u) h[u] = x8[(size_t)cc[u] * 64 + lane];
#pragma unroll
      for (int j = 0; j < 8; ++j) {
        float a = acc[j];
#pragma unroll
        for (int u = 0; u < 8; ++u) a += vv[u] * (float)h[u][j];
        acc[j] = a;
      }
    }
    for (; i + 4 <= cnt; i += 4) {
      int c0 = __shfl(key, i),     c1 = __shfl(key, i + 1);
      int c2 = __shfl(key, i + 2), c3 = __shfl(key, i + 3);
      float v0 = __shfl(val, i),     v1 = __shfl(val, i + 1);
      float v2 = __shfl(val, i + 2), v3 = __shfl(val, i + 3);
      half8 h0 = x8[(size_t)c0 * 64 + lane];
      half8 h1 = x8[(size_t)c1 * 64 + lane];
      half8 h2 = x8[(size_t)c2 * 64 + lane];
      half8 h3 = x8[(size_t)c3 * 64 + lane];
#pragma unroll
      for (int j = 0; j < 8; ++j)
        acc[j] += v0 * (float)h0[j] + v1 * (float)h1[j] + v2 * (float)h2[j] + v3 * (float)h3[j];
    }
    for (; i < cnt; ++i) {
      int c0 = __shfl(key, i);
      float v0 = __shfl(val, i);
      half8 h0 = x8[(size_t)c0 * 64 + lane];
#pragma unroll
      for (int j = 0; j < 8; ++j) acc[j] += v0 * (float)h0[j];
    }
  }

  half8 o;
#pragma unroll
  for (int j = 0; j < 8; ++j) o[j] = (_Float16)acc[j];
  ((half8*)yh)[(size_t)wid * 64 + lane] = o;  // read by GEMM -> cacheable
}

// ---------------- fully fused triple GEMM + epilogue -------------------------
// Block computes, for 128 rows x 64 cols:  agg = y@w1, trans = x@w2, gate path
// x@w3 -- all three accumulators live in registers -> epilogue fused, single
// NT store of out. m97-style staging (global_load_lds width=16, XOR chunk
// swizzle), 4 waves each 32 rows x 64 cols x 3 mats.
__global__ __launch_bounds__(256) void k_gemm_fused(
    const _Float16* __restrict__ Ax,  // xh [M][512]
    const _Float16* __restrict__ Ay,  // yh [M][512]
    const _Float16* __restrict__ BT,  // wT [1536][512], row jg = m*512 + j
    const float* __restrict__ b1, const float* __restrict__ b2,
    const float* __restrict__ b3, float* __restrict__ out, int M)
{
  __shared__ __align__(16) _Float16 ldsAx[128 * 32];
  __shared__ __align__(16) _Float16 ldsAy[128 * 32];
  __shared__ __align__(16) _Float16 ldsB[192 * 32];
  int t = threadIdx.x;
  int cb = blockIdx.x;              // col block: cols [cb*64, cb*64+64) of each mat
  int rowBase = blockIdx.y * 128;
  int w = t >> 6, lane = t & 63, lr = lane & 15, quad = lane >> 4;
  floatx4 acc[3][2][4] = {};        // [mat][rowfrag][colfrag]

  int srow0 = lane >> 2;
  int schunk = lane & 3;

  for (int k0 = 0; k0 < D; k0 += 32) {
    // stage A (xh + yh): wave w stages rows [w*32, w*32+32), 2 calls each
#pragma unroll
    for (int c = 0; c < 2; ++c) {
      int srow = w * 32 + c * 16 + srow0;
      int chunk = schunk ^ ((srow >> 1) & 3);
      int ga = rowBase + srow; if (ga >= M) ga = M - 1;
      const _Float16* gx = Ax + (size_t)ga * D + k0 + chunk * 8;
      const _Float16* gy = Ay + (size_t)ga * D + k0 + chunk * 8;
      _Float16* lx = &ldsAx[(w * 32 + c * 16) * 32];
      _Float16* ly = &ldsAy[(w * 32 + c * 16) * 32];
      __builtin_amdgcn_global_load_lds((const __attribute__((address_space(1))) void*)gx,
                                       (__attribute__((address_space(3))) void*)lx, 16, 0, 0);
      __builtin_amdgcn_global_load_lds((const __attribute__((address_space(1))) void*)gy,
                                       (__attribute__((address_space(3))) void*)ly, 16, 0, 0);
    }
    // stage B: 192 rows (3 mats x 64 cols); wave w stages rows [w*48, w*48+48)
#pragma unroll
    for (int c = 0; c < 3; ++c) {
      int srow = w * 48 + c * 16 + srow0;          // 0..191
      int chunk = schunk ^ ((srow >> 1) & 3);
      int m = srow >> 6, j = srow & 63;
      const _Float16* gB = BT + (size_t)(m * 512 + cb * 64 + j) * D + k0 + chunk * 8;
      _Float16* lB = &ldsB[(w * 48 + c * 16) * 32];
      __builtin_amdgcn_global_load_lds((const __attribute__((address_space(1))) void*)gB,
                                       (__attribute__((address_space(3))) void*)lB, 16, 0, 0);
    }
    __syncthreads();

    half8 afx[2], afy[2];
#pragma unroll
    for (int i2 = 0; i2 < 2; ++i2) {
      int r = w * 32 + i2 * 16 + lr;
      int sl = (quad ^ ((r >> 1) & 3)) << 3;
      afx[i2] = *(const half8*)&ldsAx[r * 32 + sl];
      afy[i2] = *(const half8*)&ldsAy[r * 32 + sl];
    }
#pragma unroll
    for (int m = 0; m < 3; ++m) {
      half8 bf[4];
#pragma unroll
      for (int f = 0; f < 4; ++f) {
        int r = m * 64 + f * 16 + lr;
        bf[f] = *(const half8*)&ldsB[r * 32 + ((quad ^ ((r >> 1) & 3)) << 3)];
      }
#pragma unroll
      for (int i2 = 0; i2 < 2; ++i2)
#pragma unroll
        for (int f = 0; f < 4; ++f)
          acc[m][i2][f] = __builtin_amdgcn_mfma_f32_16x16x32_f16(
              m == 0 ? afy[i2] : afx[i2], bf[f], acc[m][i2][f], 0, 0, 0);
    }
    __syncthreads();
  }

  // epilogue: C/D layout col = lane&15, row = quad*4 + reg
#pragma unroll
  for (int i2 = 0; i2 < 2; ++i2) {
    int r0 = rowBase + w * 32 + i2 * 16 + quad * 4;
#pragma unroll
    for (int f = 0; f < 4; ++f) {
      int c = cb * 64 + f * 16 + lr;
      float bb1 = b1[c], bb2 = b2[c], bb3 = b3[c];
#pragma unroll
      for (int rg = 0; rg < 4; ++rg) {
        int r = r0 + rg;
        if (r >= M) continue;
        float aggv = acc[0][i2][f][rg] + bb1;
        aggv = aggv > 0.f ? aggv : 0.f;
        float tr = acc[1][i2][f][rg] + bb2;
        float gv = acc[2][i2][f][rg] + bb3;
        gv = 1.0f / (1.0f + __expf(-gv));
        __builtin_nontemporal_store(tr + gv * (aggv - tr), &out[(size_t)r * D + c]);
      }
    }
  }
}

// ---------------- launch ----------------

extern "C" void kernel_launch(void* const* d_in, const int* in_sizes, int n_in,
                              void* d_out, int out_size, void* d_ws, size_t ws_size,
                              hipStream_t stream) {
  const float* x    = (const float*)d_in[0];
  const float* w1   = (const float*)d_in[1];
  const float* w2   = (const float*)d_in[2];
  const float* w3   = (const float*)d_in[3];
  const float* b1   = (const float*)d_in[4];
  const float* b2   = (const float*)d_in[5];
  const float* b3   = (const float*)d_in[6];
  const int*   erow = (const int*)d_in[7];
  const int*   ecol = (const int*)d_in[8];
  const float* eval = (const float*)d_in[9];
  float* out = (float*)d_out;

  int N = in_sizes[0] / D;  // 100000
  int E = in_sizes[7];      // 3200000

  char* ws = (char*)d_ws;
  size_t off = 0;
  auto take = [&](size_t bytes) -> char* {
    char* p = ws + off;
    off += (bytes + 255) & ~(size_t)255;
    return p;
  };
  _Float16* xh    = (_Float16*)take((size_t)N * D * 2);
  _Float16* yh    = (_Float16*)take((size_t)N * D * 2);
  _Float16* wT    = (_Float16*)take((size_t)3 * D * D * 2);
  int* counts     = (int*)take((size_t)N * 4);
  int* cursor     = (int*)take((size_t)N * 4);
  int* offsets    = (int*)take((size_t)(N + 1) * 4);
  int* bsums      = (int*)take(128 * 4);
  long long* edges = (long long*)take((size_t)E * 8);

  hipMemsetAsync(counts, 0, (size_t)N * 4, stream);
  hipMemsetAsync(cursor, 0, (size_t)N * 4, stream);

  int n4 = N * D / 4;
  k_f32_to_f16<<<(n4 + 255) / 256, 256, 0, stream>>>(x, xh, n4);
  k_build_wt<<<(3 * D * D + 255) / 256, 256, 0, stream>>>(w1, w2, w3, wT);
  k_count<<<(E + 255) / 256, 256, 0, stream>>>(erow, counts, E);
  int nb = (N + 1023) / 1024;
  k_scan1<<<nb, 256, 0, stream>>>(counts, offsets, bsums, N);
  k_scan2<<<1, 128, 0, stream>>>(bsums, offsets + N, nb);
  k_scan3<<<nb, 256, 0, stream>>>(offsets, bsums, N);
  k_scatter<<<(E + 255) / 256, 256, 0, stream>>>(erow, ecol, eval, offsets, cursor, edges, E);
  k_agg<<<((size_t)N * 64 + 255) / 256, 256, 0, stream>>>(xh, yh, offsets, edges, N);
  dim3 gg(D / 64, (N + 127) / 128);
  k_gemm_fused<<<gg, 256, 0, stream>>>(xh, yh, wT, b1, b2, b3, out, N);
}

// Round 3
// 1327.897 us; speedup vs baseline: 1.1421x; 1.0313x over previous
//
#include <hip/hip_runtime.h>
#include <hip/hip_bf16.h>
#include <hip/hip_fp16.h>

#define D 512

typedef _Float16 half8 __attribute__((ext_vector_type(8)));
typedef _Float16 half4v __attribute__((ext_vector_type(4)));
typedef float floatx4 __attribute__((ext_vector_type(4)));

// ---------------- conversion kernels ----------------

__global__ void k_f32_to_f16(const float* __restrict__ in, _Float16* __restrict__ out, int n4) {
  int i = blockIdx.x * blockDim.x + threadIdx.x;
  if (i >= n4) return;
  floatx4 v = __builtin_nontemporal_load((const floatx4*)in + i);
  half4v h;
  h[0] = (_Float16)v[0]; h[1] = (_Float16)v[1]; h[2] = (_Float16)v[2]; h[3] = (_Float16)v[3];
  ((half4v*)out)[i] = h;  // xh reused by agg + GEMM -> cacheable
}

// wT[jg][k] = w_m[k][j],  jg = m*512 + j  (B^T layout for MFMA)
__global__ void k_build_wt(const float* __restrict__ w1, const float* __restrict__ w2,
                           const float* __restrict__ w3, _Float16* __restrict__ wT) {
  int id = blockIdx.x * blockDim.x + threadIdx.x;
  if (id >= 3 * D * D) return;
  int jg = id >> 9;
  int k  = id & (D - 1);
  const float* w = (jg < D) ? w1 : (jg < 2 * D ? w2 : w3);
  int j = jg & (D - 1);
  wT[id] = (_Float16)w[k * D + j];
}

// ---------------- CSR build ----------------

__global__ void k_count(const int* __restrict__ row, int* __restrict__ counts, int E) {
  int i = blockIdx.x * blockDim.x + threadIdx.x;
  if (i < E) atomicAdd(&counts[row[i]], 1);
}

__global__ __launch_bounds__(256) void k_scan1(const int* __restrict__ in, int* __restrict__ out,
                                               int* __restrict__ bsums, int n) {
  __shared__ int wsum[4];
  int t = threadIdx.x, lane = t & 63, wd = t >> 6;
  int i0 = blockIdx.x * 1024 + t * 4;
  int4 c = make_int4(0, 0, 0, 0);
  if (i0 + 3 < n) c = *(const int4*)(in + i0);
  else {
    if (i0 < n) c.x = in[i0];
    if (i0 + 1 < n) c.y = in[i0 + 1];
    if (i0 + 2 < n) c.z = in[i0 + 2];
  }
  int s1 = c.x, s2 = s1 + c.y, s3 = s2 + c.z, s4 = s3 + c.w;
  int x = s4;
#pragma unroll
  for (int o = 1; o < 64; o <<= 1) { int p = __shfl_up(x, o); if (lane >= o) x += p; }
  if (lane == 63) wsum[wd] = x;
  __syncthreads();
  int wex = 0;
  for (int k = 0; k < wd; ++k) wex += wsum[k];
  int base = wex + x - s4;
  if (i0 + 3 < n) *(int4*)(out + i0) = make_int4(base, base + s1, base + s2, base + s3);
  else {
    if (i0 < n) out[i0] = base;
    if (i0 + 1 < n) out[i0 + 1] = base + s1;
    if (i0 + 2 < n) out[i0 + 2] = base + s2;
  }
  if (t == 0) bsums[blockIdx.x] = wsum[0] + wsum[1] + wsum[2] + wsum[3];
}

__global__ void k_scan2(int* __restrict__ bsums, int* __restrict__ total_out, int nb) {
  __shared__ int w0;
  int t = threadIdx.x, lane = t & 63, wd = t >> 6;
  int v = (t < nb) ? bsums[t] : 0;
  int x = v;
#pragma unroll
  for (int o = 1; o < 64; o <<= 1) { int p = __shfl_up(x, o); if (lane >= o) x += p; }
  if (wd == 0 && lane == 63) w0 = x;
  __syncthreads();
  int excl = x - v + (wd ? w0 : 0);
  if (t < nb) bsums[t] = excl;
  if (t == 127) *total_out = w0 + x;
}

__global__ __launch_bounds__(256) void k_scan3(int* __restrict__ out, const int* __restrict__ bsums, int n) {
  int t = threadIdx.x;
  int i0 = blockIdx.x * 1024 + t * 4;
  int add = bsums[blockIdx.x];
  if (i0 + 3 < n) {
    int4 v = *(int4*)(out + i0);
    v.x += add; v.y += add; v.z += add; v.w += add;
    *(int4*)(out + i0) = v;
  } else {
    for (int k = 0; k < 4; ++k) if (i0 + k < n) out[i0 + k] += add;
  }
}

__global__ void k_scatter(const int* __restrict__ row, const int* __restrict__ col,
                          const float* __restrict__ val, const int* __restrict__ offsets,
                          int* __restrict__ cursor, long long* __restrict__ edges, int E) {
  int i = blockIdx.x * blockDim.x + threadIdx.x;
  if (i >= E) return;
  int r = row[i];
  int c = __builtin_nontemporal_load(col + i);
  float v = __builtin_nontemporal_load(val + i);
  int p = offsets[r] + atomicAdd(&cursor[r], 1);
  long long pack = ((long long)(unsigned)__float_as_int(v) << 32) | (unsigned)c;
  __builtin_nontemporal_store(pack, edges + p);
}

// ---------------- sparse aggregation on xh:  y = A_sp @ xh  (f16 out) --------
// One wave per node; lane handles 8 channels; bitonic-sort 64-edge chunks by
// col; 16-deep gather batch (latency probe: helps iff k_agg is latency-bound,
// not L2-miss-BW-bound).
__global__ __launch_bounds__(256) void k_agg(
    const _Float16* __restrict__ xh, _Float16* __restrict__ yh,
    const int* __restrict__ offsets, const long long* __restrict__ edges, int n)
{
  int wid = (blockIdx.x * 256 + threadIdx.x) >> 6;
  if (wid >= n) return;
  int lane = threadIdx.x & 63;
  int s = offsets[wid], e = offsets[wid + 1];
  float acc[8] = {0, 0, 0, 0, 0, 0, 0, 0};
  const half8* x8 = (const half8*)xh;

  for (int base = s; base < e; base += 64) {
    int cnt = e - base; if (cnt > 64) cnt = 64;
    int key = 0x7fffffff; float val = 0.f;
    if (lane < cnt) {
      long long ed = __builtin_nontemporal_load(edges + base + lane);
      key = (int)(unsigned)(ed & 0xffffffffll);
      val = __int_as_float((int)(ed >> 32));
    }
#pragma unroll
    for (int size = 2; size <= 64; size <<= 1) {
#pragma unroll
      for (int stride = size >> 1; stride; stride >>= 1) {
        int pk = __shfl_xor(key, stride);
        float pv = __shfl_xor(val, stride);
        bool upper = (lane & stride) != 0;
        bool desc = (lane & size) != 0;
        bool takemax = upper != desc;
        bool swap = takemax ? (pk > key) : (pk < key);
        if (swap) { key = pk; val = pv; }
      }
    }
    int i = 0;
    // 16-deep gather: 16 independent 16B loads in flight per lane
    for (; i + 16 <= cnt; i += 16) {
      int cc[16]; float vv[16];
#pragma unroll
      for (int u = 0; u < 16; ++u) { cc[u] = __shfl(key, i + u); vv[u] = __shfl(val, i + u); }
      half8 h[16];
#pragma unroll
      for (int u = 0; u < 16; ++u) h[u] = x8[(size_t)cc[u] * 64 + lane];
#pragma unroll
      for (int j = 0; j < 8; ++j) {
        float a = acc[j];
#pragma unroll
        for (int u = 0; u < 16; ++u) a += vv[u] * (float)h[u][j];
        acc[j] = a;
      }
    }
    for (; i + 8 <= cnt; i += 8) {
      int cc[8]; float vv[8];
#pragma unroll
      for (int u = 0; u < 8; ++u) { cc[u] = __shfl(key, i + u); vv[u] = __shfl(val, i + u); }
      half8 h[8];
#pragma unroll
      for (int u = 0; u < 8; ++u) h[u] = x8[(size_t)cc[u] * 64 + lane];
#pragma unroll
      for (int j = 0; j < 8; ++j) {
        float a = acc[j];
#pragma unroll
        for (int u = 0; u < 8; ++u) a += vv[u] * (float)h[u][j];
        acc[j] = a;
      }
    }
    for (; i + 4 <= cnt; i += 4) {
      int c0 = __shfl(key, i),     c1 = __shfl(key, i + 1);
      int c2 = __shfl(key, i + 2), c3 = __shfl(key, i + 3);
      float v0 = __shfl(val, i),     v1 = __shfl(val, i + 1);
      float v2 = __shfl(val, i + 2), v3 = __shfl(val, i + 3);
      half8 h0 = x8[(size_t)c0 * 64 + lane];
      half8 h1 = x8[(size_t)c1 * 64 + lane];
      half8 h2 = x8[(size_t)c2 * 64 + lane];
      half8 h3 = x8[(size_t)c3 * 64 + lane];
#pragma unroll
      for (int j = 0; j < 8; ++j)
        acc[j] += v0 * (float)h0[j] + v1 * (float)h1[j] + v2 * (float)h2[j] + v3 * (float)h3[j];
    }
    for (; i < cnt; ++i) {
      int c0 = __shfl(key, i);
      float v0 = __shfl(val, i);
      half8 h0 = x8[(size_t)c0 * 64 + lane];
#pragma unroll
      for (int j = 0; j < 8; ++j) acc[j] += v0 * (float)h0[j];
    }
  }

  half8 o;
#pragma unroll
  for (int j = 0; j < 8; ++j) o[j] = (_Float16)acc[j];
  ((half8*)yh)[(size_t)wid * 64 + lane] = o;  // read by GEMM -> cacheable
}

// ---------------- fully fused triple GEMM + epilogue -------------------------
// Block computes, for 128 rows x 64 cols:  agg = y@w1, trans = x@w2, gate =
// sigmoid(x@w3); epilogue fused, single NT store of out.
// XCD-aware bijective swizzle (T1/m204): linear bid -> per-XCD contiguous work
// index w = (bid&7)*nrb + bid>>3; rb = w>>3, cb = w&7. The 8 cb-blocks sharing
// a rowBase run back-to-back on ONE XCD -> A-tile (xh+yh rows, 256KB) is
// fetched into that XCD's L2 once and reused 8x (A refetch 1.6GB -> ~0.2GB).
__global__ __launch_bounds__(256) void k_gemm_fused(
    const _Float16* __restrict__ Ax,  // xh [M][512]
    const _Float16* __restrict__ Ay,  // yh [M][512]
    const _Float16* __restrict__ BT,  // wT [1536][512], row jg = m*512 + j
    const float* __restrict__ b1, const float* __restrict__ b2,
    const float* __restrict__ b3, float* __restrict__ out, int M)
{
  __shared__ __align__(16) _Float16 ldsAx[128 * 32];
  __shared__ __align__(16) _Float16 ldsAy[128 * 32];
  __shared__ __align__(16) _Float16 ldsB[192 * 32];
  int t = threadIdx.x;
  int nrb = (M + 127) >> 7;
  int bid = blockIdx.x;
  int wq = (bid & 7) * nrb + (bid >> 3);   // bijection since gridDim.x = 8*nrb
  int rowBase = (wq >> 3) << 7;
  int cb = wq & 7;                          // col block: cols [cb*64, cb*64+64)
  int w = t >> 6, lane = t & 63, lr = lane & 15, quad = lane >> 4;
  floatx4 acc[3][2][4] = {};                // [mat][rowfrag][colfrag]

  int srow0 = lane >> 2;
  int schunk = lane & 3;

  for (int k0 = 0; k0 < D; k0 += 32) {
    // stage A (xh + yh): wave w stages rows [w*32, w*32+32), 2 calls each
#pragma unroll
    for (int c = 0; c < 2; ++c) {
      int srow = w * 32 + c * 16 + srow0;
      int chunk = schunk ^ ((srow >> 1) & 3);
      int ga = rowBase + srow; if (ga >= M) ga = M - 1;
      const _Float16* gx = Ax + (size_t)ga * D + k0 + chunk * 8;
      const _Float16* gy = Ay + (size_t)ga * D + k0 + chunk * 8;
      _Float16* lx = &ldsAx[(w * 32 + c * 16) * 32];
      _Float16* ly = &ldsAy[(w * 32 + c * 16) * 32];
      __builtin_amdgcn_global_load_lds((const __attribute__((address_space(1))) void*)gx,
                                       (__attribute__((address_space(3))) void*)lx, 16, 0, 0);
      __builtin_amdgcn_global_load_lds((const __attribute__((address_space(1))) void*)gy,
                                       (__attribute__((address_space(3))) void*)ly, 16, 0, 0);
    }
    // stage B: 192 rows (3 mats x 64 cols); wave w stages rows [w*48, w*48+48)
#pragma unroll
    for (int c = 0; c < 3; ++c) {
      int srow = w * 48 + c * 16 + srow0;          // 0..191
      int chunk = schunk ^ ((srow >> 1) & 3);
      int m = srow >> 6, j = srow & 63;
      const _Float16* gB = BT + (size_t)(m * 512 + cb * 64 + j) * D + k0 + chunk * 8;
      _Float16* lB = &ldsB[(w * 48 + c * 16) * 32];
      __builtin_amdgcn_global_load_lds((const __attribute__((address_space(1))) void*)gB,
                                       (__attribute__((address_space(3))) void*)lB, 16, 0, 0);
    }
    __syncthreads();

    half8 afx[2], afy[2];
#pragma unroll
    for (int i2 = 0; i2 < 2; ++i2) {
      int r = w * 32 + i2 * 16 + lr;
      int sl = (quad ^ ((r >> 1) & 3)) << 3;
      afx[i2] = *(const half8*)&ldsAx[r * 32 + sl];
      afy[i2] = *(const half8*)&ldsAy[r * 32 + sl];
    }
#pragma unroll
    for (int m = 0; m < 3; ++m) {
      half8 bf[4];
#pragma unroll
      for (int f = 0; f < 4; ++f) {
        int r = m * 64 + f * 16 + lr;
        bf[f] = *(const half8*)&ldsB[r * 32 + ((quad ^ ((r >> 1) & 3)) << 3)];
      }
#pragma unroll
      for (int i2 = 0; i2 < 2; ++i2)
#pragma unroll
        for (int f = 0; f < 4; ++f)
          acc[m][i2][f] = __builtin_amdgcn_mfma_f32_16x16x32_f16(
              m == 0 ? afy[i2] : afx[i2], bf[f], acc[m][i2][f], 0, 0, 0);
    }
    __syncthreads();
  }

  // epilogue: C/D layout col = lane&15, row = quad*4 + reg
#pragma unroll
  for (int i2 = 0; i2 < 2; ++i2) {
    int r0 = rowBase + w * 32 + i2 * 16 + quad * 4;
#pragma unroll
    for (int f = 0; f < 4; ++f) {
      int c = cb * 64 + f * 16 + lr;
      float bb1 = b1[c], bb2 = b2[c], bb3 = b3[c];
#pragma unroll
      for (int rg = 0; rg < 4; ++rg) {
        int r = r0 + rg;
        if (r >= M) continue;
        float aggv = acc[0][i2][f][rg] + bb1;
        aggv = aggv > 0.f ? aggv : 0.f;
        float tr = acc[1][i2][f][rg] + bb2;
        float gv = acc[2][i2][f][rg] + bb3;
        gv = 1.0f / (1.0f + __expf(-gv));
        __builtin_nontemporal_store(tr + gv * (aggv - tr), &out[(size_t)r * D + c]);
      }
    }
  }
}

// ---------------- launch ----------------

extern "C" void kernel_launch(void* const* d_in, const int* in_sizes, int n_in,
                              void* d_out, int out_size, void* d_ws, size_t ws_size,
                              hipStream_t stream) {
  const float* x    = (const float*)d_in[0];
  const float* w1   = (const float*)d_in[1];
  const float* w2   = (const float*)d_in[2];
  const float* w3   = (const float*)d_in[3];
  const float* b1   = (const float*)d_in[4];
  const float* b2   = (const float*)d_in[5];
  const float* b3   = (const float*)d_in[6];
  const int*   erow = (const int*)d_in[7];
  const int*   ecol = (const int*)d_in[8];
  const float* eval = (const float*)d_in[9];
  float* out = (float*)d_out;

  int N = in_sizes[0] / D;  // 100000
  int E = in_sizes[7];      // 3200000

  char* ws = (char*)d_ws;
  size_t off = 0;
  auto take = [&](size_t bytes) -> char* {
    char* p = ws + off;
    off += (bytes + 255) & ~(size_t)255;
    return p;
  };
  _Float16* xh    = (_Float16*)take((size_t)N * D * 2);
  _Float16* yh    = (_Float16*)take((size_t)N * D * 2);
  _Float16* wT    = (_Float16*)take((size_t)3 * D * D * 2);
  int* counts     = (int*)take((size_t)N * 4);
  int* cursor     = (int*)take((size_t)N * 4);
  int* offsets    = (int*)take((size_t)(N + 1) * 4);
  int* bsums      = (int*)take(128 * 4);
  long long* edges = (long long*)take((size_t)E * 8);

  hipMemsetAsync(counts, 0, (size_t)N * 4, stream);
  hipMemsetAsync(cursor, 0, (size_t)N * 4, stream);

  int n4 = N * D / 4;
  k_f32_to_f16<<<(n4 + 255) / 256, 256, 0, stream>>>(x, xh, n4);
  k_build_wt<<<(3 * D * D + 255) / 256, 256, 0, stream>>>(w1, w2, w3, wT);
  k_count<<<(E + 255) / 256, 256, 0, stream>>>(erow, counts, E);
  int nb = (N + 1023) / 1024;
  k_scan1<<<nb, 256, 0, stream>>>(counts, offsets, bsums, N);
  k_scan2<<<1, 128, 0, stream>>>(bsums, offsets + N, nb);
  k_scan3<<<nb, 256, 0, stream>>>(offsets, bsums, N);
  k_scatter<<<(E + 255) / 256, 256, 0, stream>>>(erow, ecol, eval, offsets, cursor, edges, E);
  k_agg<<<((size_t)N * 64 + 255) / 256, 256, 0, stream>>>(xh, yh, offsets, edges, N);
  int nrb = (N + 127) / 128;
  k_gemm_fused<<<nrb * 8, 256, 0, stream>>>(xh, yh, wT, b1, b2, b3, out, N);
}